// Round 9
// baseline (371.767 us; speedup 1.0000x reference)
//
#include <hip/hip_runtime.h>
#include <cstddef>
#include <cstdint>

#define S_LEN 2048
#define DMODEL 2048
#define NH 16
#define NKV 4
#define HD 128
#define BATCH 2
#define MROWS (BATCH * S_LEN) /* 4096 */
#define KVD (NKV * HD)        /* 512 */
#define QKVSTR 3072           /* fused qkv row stride (f16) */

typedef __attribute__((ext_vector_type(8))) short bf16x8;
typedef __attribute__((ext_vector_type(4))) short shortx4;
typedef __attribute__((ext_vector_type(4))) float floatx4;
typedef __attribute__((ext_vector_type(8))) _Float16 half8;
typedef __attribute__((ext_vector_type(4))) _Float16 half4;
typedef __attribute__((ext_vector_type(2))) _Float16 half2v;

#define QSCALE 0.1275310255f /* log2(e)/sqrt(128): folds softmax scale + exp2 conversion */

__device__ inline short f2bf(float f) {
  union { float f; unsigned u; } v; v.f = f;
  unsigned r = v.u + 0x7FFFu + ((v.u >> 16) & 1u); // RNE
  return (short)(r >> 16);
}

__device__ inline half2v pack2h(float lo, float hi) {
  union { decltype(__builtin_amdgcn_cvt_pkrtz(0.f, 0.f)) raw; half2v h; } u;
  u.raw = __builtin_amdgcn_cvt_pkrtz(lo, hi);
  return u.h;
}

// CK-style address-space cast idiom for direct global->LDS DMA (16B/lane).
__device__ __forceinline__ void glds16(const void* g, void* l) {
  __builtin_amdgcn_global_load_lds(
      reinterpret_cast<const int __attribute__((address_space(1)))*>(
          reinterpret_cast<uintptr_t>(g)),
      reinterpret_cast<int __attribute__((address_space(3)))*>(
          reinterpret_cast<uintptr_t>(l)),
      16, 0, 0);
}

// ---------------------------------------------------------------------------
// cast_bf16: fp32 -> bf16 elementwise (8 elems/thread).
// ---------------------------------------------------------------------------
__global__ __launch_bounds__(256) void cast_bf16(
    const float* __restrict__ x, short* __restrict__ y)
{
  const size_t i = ((size_t)blockIdx.x * 256 + threadIdx.x) * 8;
  const float4 a = *(const float4*)(x + i);
  const float4 b = *(const float4*)(x + i + 4);
  bf16x8 o;
  o[0] = f2bf(a.x); o[1] = f2bf(a.y); o[2] = f2bf(a.z); o[3] = f2bf(a.w);
  o[4] = f2bf(b.x); o[5] = f2bf(b.y); o[6] = f2bf(b.z); o[7] = f2bf(b.w);
  *(bf16x8*)(y + i) = o;
}

// ---------------------------------------------------------------------------
// tcast: W fp32 [2048][N] -> Wt bf16 [N][2048] (transpose + cast), 64x64 tile.
// ---------------------------------------------------------------------------
__global__ __launch_bounds__(256) void tcast(
    const float* __restrict__ W, short* __restrict__ Wt, int N)
{
  __shared__ float Ts[64][65];
  const int n0 = blockIdx.x * 64, k0 = blockIdx.y * 64;
  const int tid = threadIdx.x;
#pragma unroll
  for (int it = 0; it < 4; ++it) {
    const int r = it * 16 + (tid >> 4);
    *(float4*)&Ts[r][(tid & 15) * 4] =
        *(const float4*)&W[(size_t)(k0 + r) * N + n0 + (tid & 15) * 4];
  }
  __syncthreads();
  const int n = tid >> 2, kg = (tid & 3) * 16;
  bf16x8 o0, o1;
#pragma unroll
  for (int e = 0; e < 8; ++e) o0[e] = f2bf(Ts[kg + e][n]);
#pragma unroll
  for (int e = 0; e < 8; ++e) o1[e] = f2bf(Ts[kg + 8 + e][n]);
  short* dst = Wt + (size_t)(n0 + n) * DMODEL + k0 + kg;
  *(bf16x8*)dst = o0;
  *(bf16x8*)(dst + 8) = o1;
}

// ---------------------------------------------------------------------------
// gemm_swz: 256xBN-tile phase-split GEMM with T2 LDS swizzle (round-7 winner).
// ---------------------------------------------------------------------------
template <int BN, bool OUTF16>
__global__ __launch_bounds__(512, 2) void gemm_swz(
    const short* __restrict__ A, const short* __restrict__ Bt,
    void* __restrict__ Cv, int M, int N, int K)
{
  constexpr int NF = BN / 64; // n-frags per wave (wave n-span = NF*16)
  __shared__ short As[2][256 * 64];
  __shared__ short Bs[2][BN * 64];

  const int tid = threadIdx.x;
  const int lane = tid & 63;
  const int l16 = lane & 15, quad = lane >> 4;
  const int wave = tid >> 6;
  const int wmi = wave >> 2;  // 0..1 -> rows wmi*128..+128
  const int wni = wave & 3;   // 0..3 -> cols wni*(NF*16)
  const int m0 = blockIdx.y * 256, n0 = blockIdx.x * BN;

  const int srow = tid >> 3;                       // 0..63
  const int scol = ((tid & 7) ^ (srow & 7)) * 8;   // pre-swizzled source col
  const int lofs = srow * 64 + (tid & 7) * 8;      // linear LDS elem offset
  const short* Ab = A + (size_t)(m0 + srow) * K + scol;
  const short* Bb = Bt + (size_t)(n0 + srow) * K + scol;

  const int xs0 = ((0 * 4 + quad) ^ (l16 & 7)) * 8;
  const int xs1 = ((1 * 4 + quad) ^ (l16 & 7)) * 8;

  floatx4 acc[8][NF];
#pragma unroll
  for (int i = 0; i < 8; ++i)
#pragma unroll
    for (int j = 0; j < NF; ++j)
#pragma unroll
      for (int r = 0; r < 4; ++r) acc[i][j][r] = 0.f;

#pragma unroll
  for (int u = 0; u < 4; ++u)
    glds16(Ab + (size_t)(u * 64) * K, &As[0][u * 4096 + lofs]);
#pragma unroll
  for (int u = 0; u < NF; ++u)
    glds16(Bb + (size_t)(u * 64) * K, &Bs[0][u * 4096 + lofs]);
  __syncthreads();

  const int nkt = K >> 6;
  for (int kt = 0; kt < nkt; ++kt) {
    const int cur = kt & 1;
    const short* Asc = As[cur];
    const short* Bsc = Bs[cur];
    short* Asn = As[cur ^ 1];
    short* Bsn = Bs[cur ^ 1];
    const int knext = (kt + 1) << 6;
    const bool pre = (kt + 1 < nkt);

    bf16x8 bfr[NF][2];
#pragma unroll
    for (int n = 0; n < NF; ++n) {
      const int br = (wni * (NF * 16) + n * 16 + l16) * 64;
      bfr[n][0] = *(const bf16x8*)&Bsc[br + xs0];
      bfr[n][1] = *(const bf16x8*)&Bsc[br + xs1];
    }

#pragma unroll
    for (int p = 0; p < 4; ++p) {
      bf16x8 af[2][2];
#pragma unroll
      for (int i = 0; i < 2; ++i) {
        const int ar = (wmi * 128 + (p * 2 + i) * 16 + l16) * 64;
        af[i][0] = *(const bf16x8*)&Asc[ar + xs0];
        af[i][1] = *(const bf16x8*)&Asc[ar + xs1];
      }
      if (pre) {
        if (p == 0) {
          glds16(Ab + (size_t)(0 * 64) * K + knext, &Asn[0 * 4096 + lofs]);
          glds16(Ab + (size_t)(1 * 64) * K + knext, &Asn[1 * 4096 + lofs]);
        } else if (p == 1) {
          glds16(Ab + (size_t)(2 * 64) * K + knext, &Asn[2 * 4096 + lofs]);
          glds16(Ab + (size_t)(3 * 64) * K + knext, &Asn[3 * 4096 + lofs]);
        } else if (p == 2) {
          glds16(Bb + (size_t)(0 * 64) * K + knext, &Bsn[0 * 4096 + lofs]);
          if (NF == 3)
            glds16(Bb + (size_t)(1 * 64) * K + knext, &Bsn[1 * 4096 + lofs]);
        } else {
          glds16(Bb + (size_t)((NF - 1) * 64) * K + knext, &Bsn[(NF - 1) * 4096 + lofs]);
        }
      }
      __builtin_amdgcn_s_barrier();
      __builtin_amdgcn_s_setprio(1);
#pragma unroll
      for (int i = 0; i < 2; ++i)
#pragma unroll
        for (int n = 0; n < NF; ++n) {
          acc[p * 2 + i][n] = __builtin_amdgcn_mfma_f32_16x16x32_bf16(af[i][0], bfr[n][0], acc[p * 2 + i][n], 0, 0, 0);
          acc[p * 2 + i][n] = __builtin_amdgcn_mfma_f32_16x16x32_bf16(af[i][1], bfr[n][1], acc[p * 2 + i][n], 0, 0, 0);
        }
      __builtin_amdgcn_s_setprio(0);
      if (p < 3) __builtin_amdgcn_s_barrier();
    }
    __syncthreads();
  }

#pragma unroll
  for (int mi = 0; mi < 8; ++mi)
#pragma unroll
    for (int r = 0; r < 4; ++r) {
      const int row = m0 + wmi * 128 + mi * 16 + quad * 4 + r;
      if (OUTF16) {
        _Float16* cr = (_Float16*)Cv + (size_t)row * N + n0 + wni * (NF * 16) + l16;
#pragma unroll
        for (int ni = 0; ni < NF; ++ni) cr[ni * 16] = (_Float16)acc[mi][ni][r];
      } else {
        float* cr = (float*)Cv + (size_t)row * N + n0 + wni * (NF * 16) + l16;
#pragma unroll
        for (int ni = 0; ni < NF; ++ni) cr[ni * 16] = acc[mi][ni][r];
      }
    }
}

// ---------------------------------------------------------------------------
// rope_k: in-place RoPE on f16 k rows (stride QKVSTR, 4 heads). 4 rows/block.
// ---------------------------------------------------------------------------
__global__ __launch_bounds__(256) void rope_k(
    _Float16* __restrict__ kh, const float* __restrict__ cosp,
    const float* __restrict__ sinp)
{
  const int row = blockIdx.x * 4 + (threadIdx.x >> 6);
  const int sl = row & (S_LEN - 1);
  const int t = threadIdx.x & 63;
  const int h = t >> 4, g = t & 15;
  _Float16* base = kh + (size_t)row * QKVSTR + h * HD;
  const half8 x = *(const half8*)(base + 8 * g);
  const float4 c4 = *(const float4*)&cosp[sl * 64 + 4 * g];
  const float4 s4 = *(const float4*)&sinp[sl * 64 + 4 * g];
  const float p1[4] = {(float)x[0], (float)x[2], (float)x[4], (float)x[6]};
  const float p2[4] = {(float)x[1], (float)x[3], (float)x[5], (float)x[7]};
  const float cc[4] = {c4.x, c4.y, c4.z, c4.w};
  const float ss[4] = {s4.x, s4.y, s4.z, s4.w};
  __syncthreads();
  half4 o1, o2;
#pragma unroll
  for (int u = 0; u < 4; ++u) {
    o1[u] = (_Float16)(p1[u] * cc[u] - p2[u] * ss[u]);
    o2[u] = (_Float16)(p2[u] * cc[u] + p1[u] * ss[u]);
  }
  *(half4*)(base + 4 * g) = o1;
  *(half4*)(base + 64 + 4 * g) = o2;
}

// ---------------------------------------------------------------------------
// vtprep: f16 V rows (stride QKVSTR) -> f16 Vt [b][kvh][d][s], 64x64 tile.
// ---------------------------------------------------------------------------
__global__ __launch_bounds__(256) void vtprep(
    const _Float16* __restrict__ v, _Float16* __restrict__ Vt)
{
  __shared__ _Float16 Ts[64][72];
  const int s0 = blockIdx.x * 64, c0 = blockIdx.y * 64;
  const int tid = threadIdx.x;
#pragma unroll
  for (int it = 0; it < 4; ++it) {
    const int r = it * 16 + (tid >> 4);
    *(half4*)&Ts[r][(tid & 15) * 4] =
        *(const half4*)&v[(size_t)(s0 + r) * QKVSTR + c0 + (tid & 15) * 4];
  }
  __syncthreads();
  const int dr = tid >> 2, sg = tid & 3;
  const int d = c0 + dr;
  const int kvh = d >> 7, dd = d & 127;
  const int bb = s0 >> 11, sl = s0 & (S_LEN - 1);
  half8 t0, t1;
#pragma unroll
  for (int kk = 0; kk < 8; ++kk) t0[kk] = Ts[sg * 16 + kk][dr];
#pragma unroll
  for (int kk = 0; kk < 8; ++kk) t1[kk] = Ts[sg * 16 + 8 + kk][dr];
  _Float16* dst = Vt + ((size_t)(bb * NKV + kvh) * HD + dd) * S_LEN + sl + sg * 16;
  *(half8*)dst = t0;
  *(half8*)(dst + 8) = t1;
}

// ---------------------------------------------------------------------------
// MFMA flash attention v9: swapped-operand core (round-5/7 winner, 16 rows
// per wave) in SMALL 2-wave blocks for 4-blocks/CU residency.
// R8 post-mortem: the binder is chain latency x resident independent
// barrier-groups; the 512-block grid capped residency at 2 groups/CU.
//   - Block = 128 threads (2 waves) = one 32-row q-tile; kv-step 64.
//   - In-block complementary pairing over 32-row tiles: pass 0 qt'=p,
//     pass 1 qt'=63-p; trips (qt'>>1)+1 sum to exactly 33 per block.
//   - Grid 32x16x2 = 1024 uniform blocks -> 4 blocks/CU (8 waves), four
//     INDEPENDENT stage/compute pipelines interleave per CU (was 2).
//   - LDS 40448 B (= 79*512); 4 x 40448 = 161792 <= 163840 -> fits 4/CU.
// Core (QK swapped, in-lane softmax, P^T round-trip, PV swapped) unchanged.
// ---------------------------------------------------------------------------
__global__ __launch_bounds__(128, 2) void attn_mfma(
    const _Float16* __restrict__ Qh, const _Float16* __restrict__ Kr,
    const _Float16* __restrict__ Vt, const float* __restrict__ cosp,
    const float* __restrict__ sinp, short* __restrict__ aout)
{
  __shared__ _Float16 Ks[64][136];   // [kv][d], 272B rows
  __shared__ _Float16 Vs[128][72];   // [d][kv], 144B rows
  __shared__ _Float16 Ps[2][16][72]; // per-wave P^T buffer [q][kv]

  const int tid = threadIdx.x;
  const int wave = tid >> 6, lane = tid & 63;
  const int l16 = lane & 15, quad = lane >> 4;
  const int pair = blockIdx.x;       // 0..31
  const int h = blockIdx.y, b = blockIdx.z;
  const int kvh = h >> 2;

  // staging assignments (128 threads)
  const int skr = tid >> 1;            // 0..63 (K row)
  const int skc = (tid & 1) * 64;      // K col half
  const _Float16* kgp = Kr + (size_t)(b * S_LEN + skr) * QKVSTR + kvh * HD + skc;
  const int svr = tid;                 // 0..127 (V row = d)
  const _Float16* vgp = Vt + ((size_t)(b * NKV + kvh) * HD + svr) * S_LEN;

  for (int pass = 0; pass < 2; ++pass) {
    const int qt = pass ? (63 - pair) : pair; // 32-row tile index 0..63
    const int q0 = qt * 32 + wave * 16;
    const int srow = q0 + l16; // this lane's q-row

    // ---- Q B-frags with in-register RoPE + scale ----
    half8 qf[4];
    {
      const _Float16* qraw = Qh + (size_t)(b * S_LEN + srow) * QKVSTR + h * HD;
      const int co = srow * 64;
#pragma unroll
      for (int cc = 0; cc < 2; ++cc) {
        const half8 r0 = *(const half8*)(qraw + cc * 64 + quad * 16);
        const half8 r1 = *(const half8*)(qraw + cc * 64 + quad * 16 + 8);
        const float4 c0 = *(const float4*)&cosp[co + cc * 32 + quad * 8];
        const float4 c1 = *(const float4*)&cosp[co + cc * 32 + quad * 8 + 4];
        const float4 s0 = *(const float4*)&sinp[co + cc * 32 + quad * 8];
        const float4 s1 = *(const float4*)&sinp[co + cc * 32 + quad * 8 + 4];
        const float cA[8] = {c0.x, c0.y, c0.z, c0.w, c1.x, c1.y, c1.z, c1.w};
        const float sA[8] = {s0.x, s0.y, s0.z, s0.w, s1.x, s1.y, s1.z, s1.w};
#pragma unroll
        for (int j = 0; j < 8; ++j) {
          const float p1 = (float)((j < 4) ? r0[2 * j] : r1[2 * (j - 4)]);
          const float p2 = (float)((j < 4) ? r0[2 * j + 1] : r1[2 * (j - 4) + 1]);
          qf[cc][j]     = (_Float16)((p1 * cA[j] - p2 * sA[j]) * QSCALE);
          qf[cc + 2][j] = (_Float16)((p2 * cA[j] + p1 * sA[j]) * QSCALE);
        }
      }
    }

    floatx4 o[8]; // o[dblk][r]: O^T[d = dblk*16 + quad*4 + r][q = l16]
#pragma unroll
    for (int d = 0; d < 8; ++d) o[d] = (floatx4){0.f, 0.f, 0.f, 0.f};
    float m_run = -3e38f, l_run = 0.f;

    const int trips = (qt >> 1) + 1;
    for (int kt = 0; kt < trips; ++kt) {
      const int k0 = kt * 64;
      __syncthreads(); // prior frag reads (incl. previous pass) complete
      {
        const _Float16* g = kgp + (size_t)k0 * QKVSTR;
        _Float16* dst = &Ks[skr][skc];
#pragma unroll
        for (int u = 0; u < 8; ++u)
          *(half8*)(dst + u * 8) = *(const half8*)(g + u * 8);
      }
      {
        const _Float16* g = vgp + k0;
        _Float16* dst = &Vs[svr][0];
#pragma unroll
        for (int u = 0; u < 8; ++u)
          *(half8*)(dst + u * 8) = *(const half8*)(g + u * 8);
      }
      __syncthreads();

      // ---- QK^T swapped: s[i][r] = S[kv = k0 + i*16 + quad*4 + r][q = srow]
      floatx4 s[4];
      __builtin_amdgcn_s_setprio(1);
#pragma unroll
      for (int i = 0; i < 4; ++i) {
        s[i] = (floatx4){0.f, 0.f, 0.f, 0.f};
#pragma unroll
        for (int c = 0; c < 4; ++c) {
          const half8 kf = *(const half8*)&Ks[i * 16 + l16][quad * 8 + c * 32];
          s[i] = __builtin_amdgcn_mfma_f32_16x16x32_f16(kf, qf[c], s[i], 0, 0, 0);
        }
      }
      __builtin_amdgcn_s_setprio(0);

      if (kt == trips - 1) { // causal mask: kv > q (diagonal tile only)
#pragma unroll
        for (int i = 0; i < 4; ++i) {
          const int kvbase = k0 + i * 16 + quad * 4;
#pragma unroll
          for (int r = 0; r < 4; ++r)
            if (kvbase + r > srow) s[i][r] = -3.0e38f;
        }
      }

      // ---- online softmax: lane owns one q-row; 16 in-lane + 2 shfls ----
      float m0 = fmaxf(fmaxf(s[0][0], s[0][1]), fmaxf(s[0][2], s[0][3]));
      float m1 = fmaxf(fmaxf(s[1][0], s[1][1]), fmaxf(s[1][2], s[1][3]));
      float m2 = fmaxf(fmaxf(s[2][0], s[2][1]), fmaxf(s[2][2], s[2][3]));
      float m3 = fmaxf(fmaxf(s[3][0], s[3][1]), fmaxf(s[3][2], s[3][3]));
      float rm = fmaxf(fmaxf(m0, m1), fmaxf(m2, m3));
      rm = fmaxf(rm, __shfl_xor(rm, 16));
      rm = fmaxf(rm, __shfl_xor(rm, 32));
      if (rm > m_run) { // defer-rescale
        const float alpha = exp2f(m_run - rm);
        m_run = rm;
        l_run *= alpha;
#pragma unroll
        for (int d = 0; d < 8; ++d)
#pragma unroll
          for (int r = 0; r < 4; ++r) o[d][r] *= alpha;
      }
      float p[4][4];
      float rs = 0.f;
#pragma unroll
      for (int i = 0; i < 4; ++i)
#pragma unroll
        for (int r = 0; r < 4; ++r) {
          p[i][r] = exp2f(s[i][r] - m_run);
          rs += p[i][r];
        }
      rs += __shfl_xor(rs, 16);
      rs += __shfl_xor(rs, 32);
      l_run += rs;

      // ---- P^T to LDS: lane writes its own row's kv slots (8 x 4B) ----
#pragma unroll
      for (int i = 0; i < 4; ++i) {
        *(half2v*)&Ps[wave][l16][i * 16 + quad * 4]     = pack2h(p[i][0], p[i][1]);
        *(half2v*)&Ps[wave][l16][i * 16 + quad * 4 + 2] = pack2h(p[i][2], p[i][3]);
      }
      const half8 pf0 = *(const half8*)&Ps[wave][l16][quad * 8];
      const half8 pf1 = *(const half8*)&Ps[wave][l16][32 + quad * 8];

      // ---- PV swapped: o[dblk] = V^T . P^T ----
      __builtin_amdgcn_s_setprio(1);
#pragma unroll
      for (int d = 0; d < 8; ++d) {
        const half8 vf0 = *(const half8*)&Vs[d * 16 + l16][quad * 8];
        const half8 vf1 = *(const half8*)&Vs[d * 16 + l16][32 + quad * 8];
        o[d] = __builtin_amdgcn_mfma_f32_16x16x32_f16(vf0, pf0, o[d], 0, 0, 0);
        o[d] = __builtin_amdgcn_mfma_f32_16x16x32_f16(vf1, pf1, o[d], 0, 0, 0);
      }
      __builtin_amdgcn_s_setprio(0);
    }

    // ---- epilogue: lane writes row srow, 8 packed 8B stores ----
    const float inv = 1.0f / l_run;
    short* orow = aout + (size_t)(b * S_LEN + srow) * DMODEL + h * HD;
#pragma unroll
    for (int d = 0; d < 8; ++d) {
      shortx4 pk;
      pk[0] = f2bf(o[d][0] * inv);
      pk[1] = f2bf(o[d][1] * inv);
      pk[2] = f2bf(o[d][2] * inv);
      pk[3] = f2bf(o[d][3] * inv);
      *(shortx4*)(orow + d * 16 + quad * 4) = pk;
    }
  }
}

// ---------------------------------------------------------------------------
extern "C" void kernel_launch(void* const* d_in, const int* in_sizes, int n_in,
                              void* d_out, int out_size, void* d_ws, size_t ws_size,
                              hipStream_t stream) {
  const float* hs   = (const float*)d_in[0];
  const float* cosp = (const float*)d_in[2];
  const float* sinp = (const float*)d_in[3];
  const float* Wq   = (const float*)d_in[4];
  const float* Wk   = (const float*)d_in[5];
  const float* Wv   = (const float*)d_in[6];
  const float* Wo   = (const float*)d_in[7];
  float* out = (float*)d_out;

  // ws layout (58.7 MB):
  //   hsb bf16 [4096][2048] 16.8M (dead after qkv GEMM -> aliased by ao)
  //   Wt  bf16 [3072][2048] 12.6M (fused Wq|Wk|Wv transposed; later Wo)
  //   qkv f16  [4096][3072] 25.2M (q raw | k roped in-place | v)
  //   Vt  f16  [2][4][128][2048] 4.2M
  char* w = (char*)d_ws;
  short*    hsb = (short*)w;
  short*    Wt  = (short*)(w + 16777216);
  _Float16* qkv = (_Float16*)(w + 29360128);
  _Float16* Vt  = (_Float16*)(w + 54525952);
  short*    ao  = hsb; // safe alias: hsb dead after the fused qkv GEMM

  _Float16* qh = qkv;
  _Float16* kh = qkv + 2048;
  _Float16* vh = qkv + 2560;

  dim3 blk(256);
  cast_bf16<<<MROWS * DMODEL / (8 * 256), blk, 0, stream>>>(hs, hsb);
  tcast<<<dim3(DMODEL / 64, DMODEL / 64), blk, 0, stream>>>(Wq, Wt, DMODEL);
  tcast<<<dim3(KVD / 64, DMODEL / 64), blk, 0, stream>>>(Wk, Wt + (size_t)2048 * DMODEL, KVD);
  tcast<<<dim3(KVD / 64, DMODEL / 64), blk, 0, stream>>>(Wv, Wt + (size_t)2560 * DMODEL, KVD);
  gemm_swz<192, true><<<dim3(QKVSTR / 192, MROWS / 256), dim3(512), 0, stream>>>(hsb, Wt, qkv, MROWS, QKVSTR, DMODEL);
  rope_k<<<MROWS / 4, blk, 0, stream>>>(kh, cosp, sinp);
  vtprep<<<dim3(MROWS / 64, KVD / 64), blk, 0, stream>>>(vh, Vt);
  attn_mfma<<<dim3(32, NH, BATCH), dim3(128), 0, stream>>>(qh, kh, Vt, cosp, sinp, ao);
  tcast<<<dim3(DMODEL / 64, DMODEL / 64), blk, 0, stream>>>(Wo, Wt, DMODEL);
  gemm_swz<128, false><<<dim3(DMODEL / 128, MROWS / 256), dim3(512), 0, stream>>>(ao, Wt, out, MROWS, DMODEL, DMODEL);
}

// Round 10
// 320.648 us; speedup vs baseline: 1.1594x; 1.1594x over previous
//
#include <hip/hip_runtime.h>
#include <cstddef>
#include <cstdint>

#define S_LEN 2048
#define DMODEL 2048
#define NH 16
#define NKV 4
#define HD 128
#define BATCH 2
#define MROWS (BATCH * S_LEN) /* 4096 */
#define KVD (NKV * HD)        /* 512 */
#define QKVSTR 3072           /* fused qkv row stride (f16) */
#define NQT (S_LEN / 64)      /* 32 q-tiles of 64 rows */

typedef __attribute__((ext_vector_type(8))) short bf16x8;
typedef __attribute__((ext_vector_type(4))) short shortx4;
typedef __attribute__((ext_vector_type(4))) float floatx4;
typedef __attribute__((ext_vector_type(8))) _Float16 half8;
typedef __attribute__((ext_vector_type(4))) _Float16 half4;
typedef __attribute__((ext_vector_type(2))) _Float16 half2v;

#define QSCALE 0.1275310255f /* log2(e)/sqrt(128): folds softmax scale + exp2 conversion */

__device__ inline short f2bf(float f) {
  union { float f; unsigned u; } v; v.f = f;
  unsigned r = v.u + 0x7FFFu + ((v.u >> 16) & 1u); // RNE
  return (short)(r >> 16);
}

__device__ inline half2v pack2h(float lo, float hi) {
  union { decltype(__builtin_amdgcn_cvt_pkrtz(0.f, 0.f)) raw; half2v h; } u;
  u.raw = __builtin_amdgcn_cvt_pkrtz(lo, hi);
  return u.h;
}

// CK-style address-space cast idiom for direct global->LDS DMA (16B/lane).
__device__ __forceinline__ void glds16(const void* g, void* l) {
  __builtin_amdgcn_global_load_lds(
      reinterpret_cast<const int __attribute__((address_space(1)))*>(
          reinterpret_cast<uintptr_t>(g)),
      reinterpret_cast<int __attribute__((address_space(3)))*>(
          reinterpret_cast<uintptr_t>(l)),
      16, 0, 0);
}

// ---------------------------------------------------------------------------
// cast_bf16: fp32 -> bf16 elementwise (8 elems/thread).
// ---------------------------------------------------------------------------
__global__ __launch_bounds__(256) void cast_bf16(
    const float* __restrict__ x, short* __restrict__ y)
{
  const size_t i = ((size_t)blockIdx.x * 256 + threadIdx.x) * 8;
  const float4 a = *(const float4*)(x + i);
  const float4 b = *(const float4*)(x + i + 4);
  bf16x8 o;
  o[0] = f2bf(a.x); o[1] = f2bf(a.y); o[2] = f2bf(a.z); o[3] = f2bf(a.w);
  o[4] = f2bf(b.x); o[5] = f2bf(b.y); o[6] = f2bf(b.z); o[7] = f2bf(b.w);
  *(bf16x8*)(y + i) = o;
}

// ---------------------------------------------------------------------------
// tcast: W fp32 [2048][N] -> Wt bf16 [N][2048] (transpose + cast), 64x64 tile.
// ---------------------------------------------------------------------------
__global__ __launch_bounds__(256) void tcast(
    const float* __restrict__ W, short* __restrict__ Wt, int N)
{
  __shared__ float Ts[64][65];
  const int n0 = blockIdx.x * 64, k0 = blockIdx.y * 64;
  const int tid = threadIdx.x;
#pragma unroll
  for (int it = 0; it < 4; ++it) {
    const int r = it * 16 + (tid >> 4);
    *(float4*)&Ts[r][(tid & 15) * 4] =
        *(const float4*)&W[(size_t)(k0 + r) * N + n0 + (tid & 15) * 4];
  }
  __syncthreads();
  const int n = tid >> 2, kg = (tid & 3) * 16;
  bf16x8 o0, o1;
#pragma unroll
  for (int e = 0; e < 8; ++e) o0[e] = f2bf(Ts[kg + e][n]);
#pragma unroll
  for (int e = 0; e < 8; ++e) o1[e] = f2bf(Ts[kg + 8 + e][n]);
  short* dst = Wt + (size_t)(n0 + n) * DMODEL + k0 + kg;
  *(bf16x8*)dst = o0;
  *(bf16x8*)(dst + 8) = o1;
}

// ---------------------------------------------------------------------------
// gemm_swz: 256xBN-tile phase-split GEMM with T2 LDS swizzle (round-7 winner).
// ---------------------------------------------------------------------------
template <int BN, bool OUTF16>
__global__ __launch_bounds__(512, 2) void gemm_swz(
    const short* __restrict__ A, const short* __restrict__ Bt,
    void* __restrict__ Cv, int M, int N, int K)
{
  constexpr int NF = BN / 64; // n-frags per wave (wave n-span = NF*16)
  __shared__ short As[2][256 * 64];
  __shared__ short Bs[2][BN * 64];

  const int tid = threadIdx.x;
  const int lane = tid & 63;
  const int l16 = lane & 15, quad = lane >> 4;
  const int wave = tid >> 6;
  const int wmi = wave >> 2;  // 0..1 -> rows wmi*128..+128
  const int wni = wave & 3;   // 0..3 -> cols wni*(NF*16)
  const int m0 = blockIdx.y * 256, n0 = blockIdx.x * BN;

  const int srow = tid >> 3;                       // 0..63
  const int scol = ((tid & 7) ^ (srow & 7)) * 8;   // pre-swizzled source col
  const int lofs = srow * 64 + (tid & 7) * 8;      // linear LDS elem offset
  const short* Ab = A + (size_t)(m0 + srow) * K + scol;
  const short* Bb = Bt + (size_t)(n0 + srow) * K + scol;

  const int xs0 = ((0 * 4 + quad) ^ (l16 & 7)) * 8;
  const int xs1 = ((1 * 4 + quad) ^ (l16 & 7)) * 8;

  floatx4 acc[8][NF];
#pragma unroll
  for (int i = 0; i < 8; ++i)
#pragma unroll
    for (int j = 0; j < NF; ++j)
#pragma unroll
      for (int r = 0; r < 4; ++r) acc[i][j][r] = 0.f;

#pragma unroll
  for (int u = 0; u < 4; ++u)
    glds16(Ab + (size_t)(u * 64) * K, &As[0][u * 4096 + lofs]);
#pragma unroll
  for (int u = 0; u < NF; ++u)
    glds16(Bb + (size_t)(u * 64) * K, &Bs[0][u * 4096 + lofs]);
  __syncthreads();

  const int nkt = K >> 6;
  for (int kt = 0; kt < nkt; ++kt) {
    const int cur = kt & 1;
    const short* Asc = As[cur];
    const short* Bsc = Bs[cur];
    short* Asn = As[cur ^ 1];
    short* Bsn = Bs[cur ^ 1];
    const int knext = (kt + 1) << 6;
    const bool pre = (kt + 1 < nkt);

    bf16x8 bfr[NF][2];
#pragma unroll
    for (int n = 0; n < NF; ++n) {
      const int br = (wni * (NF * 16) + n * 16 + l16) * 64;
      bfr[n][0] = *(const bf16x8*)&Bsc[br + xs0];
      bfr[n][1] = *(const bf16x8*)&Bsc[br + xs1];
    }

#pragma unroll
    for (int p = 0; p < 4; ++p) {
      bf16x8 af[2][2];
#pragma unroll
      for (int i = 0; i < 2; ++i) {
        const int ar = (wmi * 128 + (p * 2 + i) * 16 + l16) * 64;
        af[i][0] = *(const bf16x8*)&Asc[ar + xs0];
        af[i][1] = *(const bf16x8*)&Asc[ar + xs1];
      }
      if (pre) {
        if (p == 0) {
          glds16(Ab + (size_t)(0 * 64) * K + knext, &Asn[0 * 4096 + lofs]);
          glds16(Ab + (size_t)(1 * 64) * K + knext, &Asn[1 * 4096 + lofs]);
        } else if (p == 1) {
          glds16(Ab + (size_t)(2 * 64) * K + knext, &Asn[2 * 4096 + lofs]);
          glds16(Ab + (size_t)(3 * 64) * K + knext, &Asn[3 * 4096 + lofs]);
        } else if (p == 2) {
          glds16(Bb + (size_t)(0 * 64) * K + knext, &Bsn[0 * 4096 + lofs]);
          if (NF == 3)
            glds16(Bb + (size_t)(1 * 64) * K + knext, &Bsn[1 * 4096 + lofs]);
        } else {
          glds16(Bb + (size_t)((NF - 1) * 64) * K + knext, &Bsn[(NF - 1) * 4096 + lofs]);
        }
      }
      __builtin_amdgcn_s_barrier();
      __builtin_amdgcn_s_setprio(1);
#pragma unroll
      for (int i = 0; i < 2; ++i)
#pragma unroll
        for (int n = 0; n < NF; ++n) {
          acc[p * 2 + i][n] = __builtin_amdgcn_mfma_f32_16x16x32_bf16(af[i][0], bfr[n][0], acc[p * 2 + i][n], 0, 0, 0);
          acc[p * 2 + i][n] = __builtin_amdgcn_mfma_f32_16x16x32_bf16(af[i][1], bfr[n][1], acc[p * 2 + i][n], 0, 0, 0);
        }
      __builtin_amdgcn_s_setprio(0);
      if (p < 3) __builtin_amdgcn_s_barrier();
    }
    __syncthreads();
  }

#pragma unroll
  for (int mi = 0; mi < 8; ++mi)
#pragma unroll
    for (int r = 0; r < 4; ++r) {
      const int row = m0 + wmi * 128 + mi * 16 + quad * 4 + r;
      if (OUTF16) {
        _Float16* cr = (_Float16*)Cv + (size_t)row * N + n0 + wni * (NF * 16) + l16;
#pragma unroll
        for (int ni = 0; ni < NF; ++ni) cr[ni * 16] = (_Float16)acc[mi][ni][r];
      } else {
        float* cr = (float*)Cv + (size_t)row * N + n0 + wni * (NF * 16) + l16;
#pragma unroll
        for (int ni = 0; ni < NF; ++ni) cr[ni * 16] = acc[mi][ni][r];
      }
    }
}

// ---------------------------------------------------------------------------
// rope_k: in-place RoPE on f16 k rows (stride QKVSTR, 4 heads). 4 rows/block.
// ---------------------------------------------------------------------------
__global__ __launch_bounds__(256) void rope_k(
    _Float16* __restrict__ kh, const float* __restrict__ cosp,
    const float* __restrict__ sinp)
{
  const int row = blockIdx.x * 4 + (threadIdx.x >> 6);
  const int sl = row & (S_LEN - 1);
  const int t = threadIdx.x & 63;
  const int h = t >> 4, g = t & 15;
  _Float16* base = kh + (size_t)row * QKVSTR + h * HD;
  const half8 x = *(const half8*)(base + 8 * g);
  const float4 c4 = *(const float4*)&cosp[sl * 64 + 4 * g];
  const float4 s4 = *(const float4*)&sinp[sl * 64 + 4 * g];
  const float p1[4] = {(float)x[0], (float)x[2], (float)x[4], (float)x[6]};
  const float p2[4] = {(float)x[1], (float)x[3], (float)x[5], (float)x[7]};
  const float cc[4] = {c4.x, c4.y, c4.z, c4.w};
  const float ss[4] = {s4.x, s4.y, s4.z, s4.w};
  __syncthreads();
  half4 o1, o2;
#pragma unroll
  for (int u = 0; u < 4; ++u) {
    o1[u] = (_Float16)(p1[u] * cc[u] - p2[u] * ss[u]);
    o2[u] = (_Float16)(p2[u] * cc[u] + p1[u] * ss[u]);
  }
  *(half4*)(base + 4 * g) = o1;
  *(half4*)(base + 64 + 4 * g) = o2;
}

// ---------------------------------------------------------------------------
// vtprep: f16 V rows (stride QKVSTR) -> f16 Vt [b][kvh][d][s], 64x64 tile.
// ---------------------------------------------------------------------------
__global__ __launch_bounds__(256) void vtprep(
    const _Float16* __restrict__ v, _Float16* __restrict__ Vt)
{
  __shared__ _Float16 Ts[64][72];
  const int s0 = blockIdx.x * 64, c0 = blockIdx.y * 64;
  const int tid = threadIdx.x;
#pragma unroll
  for (int it = 0; it < 4; ++it) {
    const int r = it * 16 + (tid >> 4);
    *(half4*)&Ts[r][(tid & 15) * 4] =
        *(const half4*)&v[(size_t)(s0 + r) * QKVSTR + c0 + (tid & 15) * 4];
  }
  __syncthreads();
  const int dr = tid >> 2, sg = tid & 3;
  const int d = c0 + dr;
  const int kvh = d >> 7, dd = d & 127;
  const int bb = s0 >> 11, sl = s0 & (S_LEN - 1);
  half8 t0, t1;
#pragma unroll
  for (int kk = 0; kk < 8; ++kk) t0[kk] = Ts[sg * 16 + kk][dr];
#pragma unroll
  for (int kk = 0; kk < 8; ++kk) t1[kk] = Ts[sg * 16 + 8 + kk][dr];
  _Float16* dst = Vt + ((size_t)(bb * NKV + kvh) * HD + dd) * S_LEN + sl + sg * 16;
  *(half8*)dst = t0;
  *(half8*)(dst + 8) = t1;
}

// ---------------------------------------------------------------------------
// MFMA flash attention v10: round-7 winner geometry EXACTLY (paired 512-block
// grid, 4 waves x 16 q-rows, single-buffered K/V, 2 barriers/iter, swapped-
// operand core) with ONE change: K/V staging via glds16 DMA instead of
// register loads + ds_writes. Removes ~16 issue slots + 16 staging VGPRs per
// thread-iter. glds16 needs linear LDS dests -> unpadded Ks[64][128] /
// Vs[128][64] with gemm_swz-style XOR slot swizzle (key = row&7): LDS slot s
// of row r holds global col-slot s^(r&7); staged by pre-XOR'ing the per-lane
// GLOBAL source column (legal: glds16 source IS per-lane), read back with the
// same XOR. Bank profile identical to the old padded layout (8 lanes/slot =
// structural b128 floor). LDS 45056 -> 41984 B.
// ---------------------------------------------------------------------------
__global__ __launch_bounds__(256, 3) void attn_mfma(
    const _Float16* __restrict__ Qh, const _Float16* __restrict__ Kr,
    const _Float16* __restrict__ Vt, const float* __restrict__ cosp,
    const float* __restrict__ sinp, short* __restrict__ aout)
{
  __shared__ _Float16 Ks[64 * 128];  // [kv][d], XOR-swizzled 16B slots
  __shared__ _Float16 Vs[128 * 64];  // [d][kv], XOR-swizzled 16B slots
  __shared__ _Float16 Ps[4][16][72]; // per-wave P^T buffer [q][kv] (padded)

  const int tid = threadIdx.x;
  const int wave = tid >> 6, lane = tid & 63;
  const int l16 = lane & 15, quad = lane >> 4;
  const int pair = blockIdx.x;
  const int h = blockIdx.y, b = blockIdx.z;
  const int kvh = h >> 2;

  // glds16 staging. K: call c covers slots c*256+tid -> row = c*16 + (tid>>4),
  // slot = tid&15, dst = Ks + (c*256+tid)*8 halfs (linear per wave). Source
  // col pre-XOR'd by row&7 = (tid>>4)&7. V: row = c*32 + (tid>>3), slot =
  // tid&7, key = (tid>>3)&7.
  const int kxc = ((tid & 15) ^ ((tid >> 4) & 7)) * 8;
  const int vxc = ((tid & 7) ^ ((tid >> 3) & 7)) * 8;
  const _Float16* kgp = Kr + (size_t)(b * S_LEN + (tid >> 4)) * QKVSTR + kvh * HD + kxc;
  const _Float16* vgp = Vt + ((size_t)(b * NKV + kvh) * HD + (tid >> 3)) * S_LEN + vxc;
  _Float16* kdst = Ks + tid * 8;
  _Float16* vdst = Vs + tid * 8;
  const int xq = l16 & 7; // read-side XOR key

  for (int pass = 0; pass < 2; ++pass) {
    const int qt = pass ? (NQT - 1 - pair) : pair;
    const int q0 = qt * 64 + wave * 16;
    const int srow = q0 + l16; // this lane's q-row

    // ---- Q B-frags with in-register RoPE + scale ----
    half8 qf[4];
    {
      const _Float16* qraw = Qh + (size_t)(b * S_LEN + srow) * QKVSTR + h * HD;
      const int co = srow * 64;
#pragma unroll
      for (int cc = 0; cc < 2; ++cc) {
        const half8 r0 = *(const half8*)(qraw + cc * 64 + quad * 16);
        const half8 r1 = *(const half8*)(qraw + cc * 64 + quad * 16 + 8);
        const float4 c0 = *(const float4*)&cosp[co + cc * 32 + quad * 8];
        const float4 c1 = *(const float4*)&cosp[co + cc * 32 + quad * 8 + 4];
        const float4 s0 = *(const float4*)&sinp[co + cc * 32 + quad * 8];
        const float4 s1 = *(const float4*)&sinp[co + cc * 32 + quad * 8 + 4];
        const float cA[8] = {c0.x, c0.y, c0.z, c0.w, c1.x, c1.y, c1.z, c1.w};
        const float sA[8] = {s0.x, s0.y, s0.z, s0.w, s1.x, s1.y, s1.z, s1.w};
#pragma unroll
        for (int j = 0; j < 8; ++j) {
          const float p1 = (float)((j < 4) ? r0[2 * j] : r1[2 * (j - 4)]);
          const float p2 = (float)((j < 4) ? r0[2 * j + 1] : r1[2 * (j - 4) + 1]);
          qf[cc][j]     = (_Float16)((p1 * cA[j] - p2 * sA[j]) * QSCALE);
          qf[cc + 2][j] = (_Float16)((p2 * cA[j] + p1 * sA[j]) * QSCALE);
        }
      }
    }

    floatx4 o[8]; // o[dblk][r]: O^T[d = dblk*16 + quad*4 + r][q = l16]
#pragma unroll
    for (int d = 0; d < 8; ++d) o[d] = (floatx4){0.f, 0.f, 0.f, 0.f};
    float m_run = -3e38f, l_run = 0.f;

    for (int kt = 0; kt <= qt; ++kt) {
      const int k0 = kt * 64;
      __syncthreads(); // prior frag reads (incl. previous pass) complete
#pragma unroll
      for (int c = 0; c < 4; ++c)
        glds16(kgp + (size_t)(k0 + c * 16) * QKVSTR, kdst + c * 2048);
#pragma unroll
      for (int c = 0; c < 4; ++c)
        glds16(vgp + (size_t)(c * 32) * S_LEN + k0, vdst + c * 2048);
      __syncthreads(); // implicit vmcnt(0) drains the DMA

      // ---- QK^T swapped: s[i][r] = S[kv = k0 + i*16 + quad*4 + r][q = srow]
      floatx4 s[4];
      __builtin_amdgcn_s_setprio(1);
#pragma unroll
      for (int i = 0; i < 4; ++i) {
        s[i] = (floatx4){0.f, 0.f, 0.f, 0.f};
#pragma unroll
        for (int c = 0; c < 4; ++c) {
          const half8 kf = *(const half8*)&Ks[(i * 16 + l16) * 128 + ((quad + 4 * c) ^ xq) * 8];
          s[i] = __builtin_amdgcn_mfma_f32_16x16x32_f16(kf, qf[c], s[i], 0, 0, 0);
        }
      }
      __builtin_amdgcn_s_setprio(0);

      if (kt == qt) { // causal mask: kv > q
#pragma unroll
        for (int i = 0; i < 4; ++i) {
          const int kvbase = k0 + i * 16 + quad * 4;
#pragma unroll
          for (int r = 0; r < 4; ++r)
            if (kvbase + r > srow) s[i][r] = -3.0e38f;
        }
      }

      // ---- online softmax: lane owns one q-row; 16 in-lane + 2 shfls ----
      float m0 = fmaxf(fmaxf(s[0][0], s[0][1]), fmaxf(s[0][2], s[0][3]));
      float m1 = fmaxf(fmaxf(s[1][0], s[1][1]), fmaxf(s[1][2], s[1][3]));
      float m2 = fmaxf(fmaxf(s[2][0], s[2][1]), fmaxf(s[2][2], s[2][3]));
      float m3 = fmaxf(fmaxf(s[3][0], s[3][1]), fmaxf(s[3][2], s[3][3]));
      float rm = fmaxf(fmaxf(m0, m1), fmaxf(m2, m3));
      rm = fmaxf(rm, __shfl_xor(rm, 16));
      rm = fmaxf(rm, __shfl_xor(rm, 32));
      if (rm > m_run) { // defer-rescale
        const float alpha = exp2f(m_run - rm);
        m_run = rm;
        l_run *= alpha;
#pragma unroll
        for (int d = 0; d < 8; ++d)
#pragma unroll
          for (int r = 0; r < 4; ++r) o[d][r] *= alpha;
      }
      float p[4][4];
      float rs = 0.f;
#pragma unroll
      for (int i = 0; i < 4; ++i)
#pragma unroll
        for (int r = 0; r < 4; ++r) {
          p[i][r] = exp2f(s[i][r] - m_run);
          rs += p[i][r];
        }
      rs += __shfl_xor(rs, 16);
      rs += __shfl_xor(rs, 32);
      l_run += rs;

      // ---- P^T to LDS: lane writes its own row's kv slots (8 x 4B) ----
#pragma unroll
      for (int i = 0; i < 4; ++i) {
        *(half2v*)&Ps[wave][l16][i * 16 + quad * 4]     = pack2h(p[i][0], p[i][1]);
        *(half2v*)&Ps[wave][l16][i * 16 + quad * 4 + 2] = pack2h(p[i][2], p[i][3]);
      }
      const half8 pf0 = *(const half8*)&Ps[wave][l16][quad * 8];
      const half8 pf1 = *(const half8*)&Ps[wave][l16][32 + quad * 8];

      // ---- PV swapped: o[dblk] = V^T . P^T ----
      __builtin_amdgcn_s_setprio(1);
#pragma unroll
      for (int d = 0; d < 8; ++d) {
        const half8 vf0 = *(const half8*)&Vs[(d * 16 + l16) * 64 + (quad ^ xq) * 8];
        const half8 vf1 = *(const half8*)&Vs[(d * 16 + l16) * 64 + ((quad + 4) ^ xq) * 8];
        o[d] = __builtin_amdgcn_mfma_f32_16x16x32_f16(vf0, pf0, o[d], 0, 0, 0);
        o[d] = __builtin_amdgcn_mfma_f32_16x16x32_f16(vf1, pf1, o[d], 0, 0, 0);
      }
      __builtin_amdgcn_s_setprio(0);
    }

    // ---- epilogue: lane writes row srow, 8 packed 8B stores ----
    const float inv = 1.0f / l_run;
    short* orow = aout + (size_t)(b * S_LEN + srow) * DMODEL + h * HD;
#pragma unroll
    for (int d = 0; d < 8; ++d) {
      shortx4 pk;
      pk[0] = f2bf(o[d][0] * inv);
      pk[1] = f2bf(o[d][1] * inv);
      pk[2] = f2bf(o[d][2] * inv);
      pk[3] = f2bf(o[d][3] * inv);
      *(shortx4*)(orow + d * 16 + quad * 4) = pk;
    }
  }
}

// ---------------------------------------------------------------------------
extern "C" void kernel_launch(void* const* d_in, const int* in_sizes, int n_in,
                              void* d_out, int out_size, void* d_ws, size_t ws_size,
                              hipStream_t stream) {
  const float* hs   = (const float*)d_in[0];
  const float* cosp = (const float*)d_in[2];
  const float* sinp = (const float*)d_in[3];
  const float* Wq   = (const float*)d_in[4];
  const float* Wk   = (const float*)d_in[5];
  const float* Wv   = (const float*)d_in[6];
  const float* Wo   = (const float*)d_in[7];
  float* out = (float*)d_out;

  // ws layout (58.7 MB):
  //   hsb bf16 [4096][2048] 16.8M (dead after qkv GEMM -> aliased by ao)
  //   Wt  bf16 [3072][2048] 12.6M (fused Wq|Wk|Wv transposed; later Wo)
  //   qkv f16  [4096][3072] 25.2M (q raw | k roped in-place | v)
  //   Vt  f16  [2][4][128][2048] 4.2M
  char* w = (char*)d_ws;
  short*    hsb = (short*)w;
  short*    Wt  = (short*)(w + 16777216);
  _Float16* qkv = (_Float16*)(w + 29360128);
  _Float16* Vt  = (_Float16*)(w + 54525952);
  short*    ao  = hsb; // safe alias: hsb dead after the fused qkv GEMM

  _Float16* qh = qkv;
  _Float16* kh = qkv + 2048;
  _Float16* vh = qkv + 2560;

  dim3 blk(256);
  cast_bf16<<<MROWS * DMODEL / (8 * 256), blk, 0, stream>>>(hs, hsb);
  tcast<<<dim3(DMODEL / 64, DMODEL / 64), blk, 0, stream>>>(Wq, Wt, DMODEL);
  tcast<<<dim3(KVD / 64, DMODEL / 64), blk, 0, stream>>>(Wk, Wt + (size_t)2048 * DMODEL, KVD);
  tcast<<<dim3(KVD / 64, DMODEL / 64), blk, 0, stream>>>(Wv, Wt + (size_t)2560 * DMODEL, KVD);
  gemm_swz<192, true><<<dim3(QKVSTR / 192, MROWS / 256), dim3(512), 0, stream>>>(hsb, Wt, qkv, MROWS, QKVSTR, DMODEL);
  rope_k<<<MROWS / 4, blk, 0, stream>>>(kh, cosp, sinp);
  vtprep<<<dim3(MROWS / 64, KVD / 64), blk, 0, stream>>>(vh, Vt);
  attn_mfma<<<dim3(NQT / 2, NH, BATCH), blk, 0, stream>>>(qh, kh, Vt, cosp, sinp, ao);
  tcast<<<dim3(DMODEL / 64, DMODEL / 64), blk, 0, stream>>>(Wo, Wt, DMODEL);
  gemm_swz<128, false><<<dim3(DMODEL / 128, MROWS / 256), dim3(512), 0, stream>>>(ao, Wt, out, MROWS, DMODEL, DMODEL);
}